// Round 2
// baseline (20624.702 us; speedup 1.0000x reference)
//
#include <hip/hip_runtime.h>
#include <cstdint>
#include <cstddef>

#define TT 512
#define BB 64
#define HH 256
#define NG 1024
#define DI 768
#define KY 32

__device__ __forceinline__ float sigf(float x) {
    return __fdividef(1.f, 1.f + __expf(-x));
}
__device__ __forceinline__ float tanhfast(float x) {
    return fmaf(2.f, sigf(2.f * x), -1.f);
}

// ---------------------------------------------------------------------------
// Kernel A: G_pre[tl][b][j] = sents[b][t0+tl][:] @ Wih[j][32:800]^T + bih[j]+bhh[j]
// ---------------------------------------------------------------------------
__global__ __launch_bounds__(256) void kgemm(
    const float* __restrict__ sents, const float* __restrict__ Wih,
    const float* __restrict__ bih, const float* __restrict__ bhh,
    float* __restrict__ gpre, int t0)
{
    __shared__ float As[16][68];
    __shared__ float Bs[16][64];
    const int tid = threadIdx.x;
    const int tl = blockIdx.y;
    const int jb = blockIdx.x * 64;
    const int tx = tid & 15, ty = tid >> 4;
    const int lr = tid >> 2, kq = tid & 3;

    float acc[4][4];
#pragma unroll
    for (int m = 0; m < 4; ++m)
#pragma unroll
        for (int n = 0; n < 4; ++n) acc[m][n] = 0.f;

    const float* arow = sents + ((size_t)lr * TT + t0 + tl) * DI;
    const float* brow = Wih + (size_t)(jb + lr) * 800 + KY;

    for (int k0 = 0; k0 < DI; k0 += 16) {
        float4 av = *(const float4*)(arow + k0 + kq * 4);
        float4 bv = *(const float4*)(brow + k0 + kq * 4);
        __syncthreads();
        As[kq * 4 + 0][lr] = av.x; As[kq * 4 + 1][lr] = av.y;
        As[kq * 4 + 2][lr] = av.z; As[kq * 4 + 3][lr] = av.w;
        Bs[kq * 4 + 0][lr] = bv.x; Bs[kq * 4 + 1][lr] = bv.y;
        Bs[kq * 4 + 2][lr] = bv.z; Bs[kq * 4 + 3][lr] = bv.w;
        __syncthreads();
#pragma unroll
        for (int k = 0; k < 16; ++k) {
            float4 a4 = *(const float4*)&As[k][ty * 4];
            float4 b4 = *(const float4*)&Bs[k][tx * 4];
            acc[0][0] = fmaf(a4.x, b4.x, acc[0][0]);
            acc[0][1] = fmaf(a4.x, b4.y, acc[0][1]);
            acc[0][2] = fmaf(a4.x, b4.z, acc[0][2]);
            acc[0][3] = fmaf(a4.x, b4.w, acc[0][3]);
            acc[1][0] = fmaf(a4.y, b4.x, acc[1][0]);
            acc[1][1] = fmaf(a4.y, b4.y, acc[1][1]);
            acc[1][2] = fmaf(a4.y, b4.z, acc[1][2]);
            acc[1][3] = fmaf(a4.y, b4.w, acc[1][3]);
            acc[2][0] = fmaf(a4.z, b4.x, acc[2][0]);
            acc[2][1] = fmaf(a4.z, b4.y, acc[2][1]);
            acc[2][2] = fmaf(a4.z, b4.z, acc[2][2]);
            acc[2][3] = fmaf(a4.z, b4.w, acc[2][3]);
            acc[3][0] = fmaf(a4.w, b4.x, acc[3][0]);
            acc[3][1] = fmaf(a4.w, b4.y, acc[3][1]);
            acc[3][2] = fmaf(a4.w, b4.z, acc[3][2]);
            acc[3][3] = fmaf(a4.w, b4.w, acc[3][3]);
        }
    }
    const int j0 = jb + tx * 4;
    float4 bias4;
    bias4.x = bih[j0 + 0] + bhh[j0 + 0];
    bias4.y = bih[j0 + 1] + bhh[j0 + 1];
    bias4.z = bih[j0 + 2] + bhh[j0 + 2];
    bias4.w = bih[j0 + 3] + bhh[j0 + 3];
#pragma unroll
    for (int m = 0; m < 4; ++m) {
        int row = ty * 4 + m;
        float4 o;
        o.x = acc[m][0] + bias4.x; o.y = acc[m][1] + bias4.y;
        o.z = acc[m][2] + bias4.z; o.w = acc[m][3] + bias4.w;
        *(float4*)(gpre + ((size_t)tl * BB + row) * NG + j0) = o;
    }
}

// ---------------------------------------------------------------------------
// Kernel S: SHi[tl][b][k] = sents[b][t0+tl][:] @ Waff[k][256:1024]^T + baff[k]
// ---------------------------------------------------------------------------
__global__ __launch_bounds__(256) void kshi(
    const float* __restrict__ sents, const float* __restrict__ Waff,
    const float* __restrict__ baff, float* __restrict__ shi, int t0)
{
    const int tid = threadIdx.x;
    const int lane = tid & 63;
    const int r = blockIdx.x * 4 + (tid >> 6);
    const int b = r & 63, tl = r >> 6;
    const float* hi = sents + ((size_t)b * TT + t0 + tl) * DI;
    float p0 = 0.f, p1 = 0.f;
#pragma unroll
    for (int kk = 0; kk < 12; ++kk) {
        int k = kk * 64 + lane;
        float x = hi[k];
        p0 = fmaf(x, Waff[HH + k], p0);
        p1 = fmaf(x, Waff[NG + HH + k], p1);
    }
#pragma unroll
    for (int off = 32; off >= 1; off >>= 1) {
        p0 += __shfl_xor(p0, off, 64);
        p1 += __shfl_xor(p1, off, 64);
    }
    if (lane == 0) {
        shi[(size_t)r * 2 + 0] = p0 + baff[0];
        shi[(size_t)r * 2 + 1] = p1 + baff[1];
    }
}

// ---------------------------------------------------------------------------
// init: zero the per-(b,g) step flags (ws is poisoned 0xAA before every run)
// ---------------------------------------------------------------------------
__global__ void kinit(int* __restrict__ flg) {
    flg[threadIdx.x] = 0;
}

// ---------------------------------------------------------------------------
// krec2: recurrence split 4 ways per batch element.
// grid 256 = (g = blk>>6) x (b = blk&63); 512 threads (8 waves).
// WG (g,b) owns h-dims jglob in [64g, 64g+64): weights for 4 gates x 64 rows
// x K=256 = 128 VGPRs/thread (thread = (jh = w*8+(lane&7), kq = lane>>3),
// owns K-slice [32*kq, 32*kq+32) of rows gate*256 + jglob).
// Per step: register matvec + shfl_xor(8,16,32) K-reduce; h-slice + score
// partial published via device-scope mailboxes (IF$ coherent) + monotonic
// flag; partners polled; all 4 WGs recompute identical score totals ->
// identical argmax -> identical tag feedback. No grid-wide sync.
// ---------------------------------------------------------------------------
__global__ __launch_bounds__(512, 2) void krec2(
    const float* __restrict__ gpre,   // [Tc][64][1024]
    const float* __restrict__ shi,    // [Tc][64][2] (baff folded in)
    const float* __restrict__ Whh,    // [1024][256]
    const float* __restrict__ mask,   // [64][512]
    float* __restrict__ out,          // [64][512][2]
    float* __restrict__ sh, float* __restrict__ sc, int* __restrict__ sp,
    int* __restrict__ flg,            // [64][4]
    float* __restrict__ hbox,         // [2][64][4][64]
    float* __restrict__ sbox,         // [2][64][4][2]
    const float* __restrict__ Wih, const float* __restrict__ tag,
    const float* __restrict__ Waff,
    int t0, int Tc, int first)
{
    const int blk = blockIdx.x;
    const int g = blk >> 6, b = blk & 63;
    const int tid = threadIdx.x;
    const int w = tid >> 6, lane = tid & 63;
    const int jl = lane & 7, kq = lane >> 3;
    const int jh = w * 8 + jl;        // local h-dim 0..63
    const int jglob = g * 64 + jh;    // global h-dim

    __shared__ float hk[8 * 36];      // full h[256], K-octant-major, pad 36
    __shared__ float P[2][4][64];     // tag-feedback precompute for this slice
    __shared__ float tg[2][KY];
    __shared__ float red[8][2];
    __shared__ float sred[4][2];

    // ---- Whh slice into registers: 32 float4 = 128 VGPRs ----
    float4 wreg[4][8];
#pragma unroll
    for (int gt = 0; gt < 4; ++gt) {
        const float4* src = (const float4*)(Whh + (size_t)(gt * HH + jglob) * HH + kq * 32);
#pragma unroll
        for (int kk = 0; kk < 8; ++kk) wreg[gt][kk] = src[kk];
    }
    const float waff0 = Waff[jglob];
    const float waff1 = Waff[NG + jglob];

    if (tid < 2 * KY) tg[tid >> 5][tid & 31] = tag[tid];
    __syncthreads();
    // P[r][gt][j2] = tag_em[r] @ Wih[gt*256 + 64g + j2][0:32]^T
    {
        int r = tid >> 8, rem = tid & 255, gt = rem >> 6, j2 = rem & 63;
        int row = gt * HH + g * 64 + j2;
        const float4* wr = (const float4*)(Wih + (size_t)row * 800);
        float s = 0.f;
#pragma unroll
        for (int kk = 0; kk < 8; ++kk) {
            float4 v = wr[kk];
            s = fmaf(v.x, tg[r][kk * 4 + 0], s);
            s = fmaf(v.y, tg[r][kk * 4 + 1], s);
            s = fmaf(v.z, tg[r][kk * 4 + 2], s);
            s = fmaf(v.w, tg[r][kk * 4 + 3], s);
        }
        P[r][gt][j2] = s;
    }

    float hreg, creg; int pred;
    if (first) {
        hreg = 0.f; creg = 0.f; pred = -1;
        if (tid < 72) ((float4*)hk)[tid] = make_float4(0.f, 0.f, 0.f, 0.f);
    } else {
        hreg = sh[(size_t)b * HH + jglob];
        creg = sc[(size_t)b * HH + jglob];
        pred = sp[b];
        if (tid < HH) hk[(tid >> 5) * 36 + (tid & 31)] = sh[(size_t)b * HH + tid];
    }
    __syncthreads();

    for (int tl = 0; tl < Tc; ++tl) {
        const int t = t0 + tl;
        const int p = t & 1;

        // prefetch (independent of h)
        const float* gp = gpre + ((size_t)tl * BB + b) * NG;
        float gp0 = gp[0 * HH + jglob];
        float gp1 = gp[1 * HH + jglob];
        float gp2 = gp[2 * HH + jglob];
        float gp3 = gp[3 * HH + jglob];
        float mi = mask[(size_t)b * TT + t];
        float pv0 = 0.f, pv1 = 0.f, pv2 = 0.f, pv3 = 0.f;
        if (pred >= 0) {
            pv0 = P[pred][0][jh]; pv1 = P[pred][1][jh];
            pv2 = P[pred][2][jh]; pv3 = P[pred][3][jh];
        }

        // ---- matvec: K-octant [32kq, 32kq+32) of 4 gate rows ----
        float a0 = 0.f, a1 = 0.f, a2 = 0.f, a3 = 0.f;
        const float4* h4 = (const float4*)(hk + kq * 36);
#pragma unroll
        for (int kk = 0; kk < 8; ++kk) {
            float4 hv = h4[kk];
            a0 = fmaf(wreg[0][kk].x, hv.x, a0); a0 = fmaf(wreg[0][kk].y, hv.y, a0);
            a0 = fmaf(wreg[0][kk].z, hv.z, a0); a0 = fmaf(wreg[0][kk].w, hv.w, a0);
            a1 = fmaf(wreg[1][kk].x, hv.x, a1); a1 = fmaf(wreg[1][kk].y, hv.y, a1);
            a1 = fmaf(wreg[1][kk].z, hv.z, a1); a1 = fmaf(wreg[1][kk].w, hv.w, a1);
            a2 = fmaf(wreg[2][kk].x, hv.x, a2); a2 = fmaf(wreg[2][kk].y, hv.y, a2);
            a2 = fmaf(wreg[2][kk].z, hv.z, a2); a2 = fmaf(wreg[2][kk].w, hv.w, a2);
            a3 = fmaf(wreg[3][kk].x, hv.x, a3); a3 = fmaf(wreg[3][kk].y, hv.y, a3);
            a3 = fmaf(wreg[3][kk].z, hv.z, a3); a3 = fmaf(wreg[3][kk].w, hv.w, a3);
        }
        // reduce over kq (lane bits 3,4,5)
        a0 += __shfl_xor(a0, 8, 64); a0 += __shfl_xor(a0, 16, 64); a0 += __shfl_xor(a0, 32, 64);
        a1 += __shfl_xor(a1, 8, 64); a1 += __shfl_xor(a1, 16, 64); a1 += __shfl_xor(a1, 32, 64);
        a2 += __shfl_xor(a2, 8, 64); a2 += __shfl_xor(a2, 16, 64); a2 += __shfl_xor(a2, 32, 64);
        a3 += __shfl_xor(a3, 8, 64); a3 += __shfl_xor(a3, 16, 64); a3 += __shfl_xor(a3, 32, 64);

        float gi = a0 + gp0 + pv0;
        float gf = a1 + gp1 + pv1;
        float gg = a2 + gp2 + pv2;
        float go = a3 + gp3 + pv3;
        float ig = sigf(gi), fg = sigf(gf);
        float g2 = tanhfast(gg), og = sigf(go);
        float cn = fmaf(fg, creg, ig * g2);
        float hn = og * tanhfast(cn);
        float ho = hn * mi + hreg * (1.f - mi);
        float co = cn * mi + creg * (1.f - mi);

        __syncthreads();   // B0: everyone done reading hk this step

        if (kq == 0) {     // one writer per jh (lanes 0..7 of each wave)
            hk[(jglob >> 5) * 36 + (jglob & 31)] = ho;
            __hip_atomic_store(&hbox[((size_t)(p * BB + b) * 4 + g) * 64 + jh], ho,
                               __ATOMIC_RELAXED, __HIP_MEMORY_SCOPE_AGENT);
        }
        hreg = ho; creg = co;

        // score partial over this WG's 64 h-dims (pre-mask h_new)
        float p0 = (kq == 0) ? hn * waff0 : 0.f;
        float p1 = (kq == 0) ? hn * waff1 : 0.f;
#pragma unroll
        for (int off = 32; off >= 1; off >>= 1) {
            p0 += __shfl_xor(p0, off, 64);
            p1 += __shfl_xor(p1, off, 64);
        }
        if (lane == 0) { red[w][0] = p0; red[w][1] = p1; }
        if (kq == 0) __threadfence();   // drain each writer's hbox stores
        __syncthreads();   // B1

        if (tid == 0) {
            float s0 = red[0][0], s1 = red[0][1];
#pragma unroll
            for (int wv = 1; wv < 8; ++wv) { s0 += red[wv][0]; s1 += red[wv][1]; }
            __hip_atomic_store(&sbox[((size_t)(p * BB + b) * 4 + g) * 2 + 0], s0,
                               __ATOMIC_RELAXED, __HIP_MEMORY_SCOPE_AGENT);
            __hip_atomic_store(&sbox[((size_t)(p * BB + b) * 4 + g) * 2 + 1], s1,
                               __ATOMIC_RELAXED, __HIP_MEMORY_SCOPE_AGENT);
            __threadfence();
            __hip_atomic_store(&flg[b * 4 + g], t + 1,
                               __ATOMIC_RELEASE, __HIP_MEMORY_SCOPE_AGENT);
            sred[g][0] = s0; sred[g][1] = s1;
        }
        if (tid >= 1 && tid < 4) {      // poll the 3 partners
            int pg = (g + tid) & 3;
            while (__hip_atomic_load(&flg[b * 4 + pg],
                                     __ATOMIC_ACQUIRE, __HIP_MEMORY_SCOPE_AGENT) < t + 1)
                __builtin_amdgcn_s_sleep(1);
        }
        __syncthreads();   // B2: partner flags observed

        if (tid < 192) {   // fetch 3 partner h-slices into LDS
            int pg = (g + 1 + (tid >> 6)) & 3, j2 = tid & 63;
            float v = __hip_atomic_load(&hbox[((size_t)(p * BB + b) * 4 + pg) * 64 + j2],
                                        __ATOMIC_RELAXED, __HIP_MEMORY_SCOPE_AGENT);
            int kf = pg * 64 + j2;
            hk[(kf >> 5) * 36 + (kf & 31)] = v;
        } else if (tid < 198) {
            int i = tid - 192, pg = (g + 1 + (i >> 1)) & 3, c = i & 1;
            sred[pg][c] = __hip_atomic_load(&sbox[((size_t)(p * BB + b) * 4 + pg) * 2 + c],
                                            __ATOMIC_RELAXED, __HIP_MEMORY_SCOPE_AGENT);
        }
        __syncthreads();   // B3: hk + sred complete

        // identical total in all 4 WGs (fixed summation order, identical bits)
        float s0 = ((sred[0][0] + sred[1][0]) + sred[2][0]) + sred[3][0];
        float s1 = ((sred[0][1] + sred[1][1]) + sred[2][1]) + sred[3][1];
        const float* s2 = shi + ((size_t)tl * BB + b) * 2;
        float ts0 = s0 + s2[0], ts1 = s1 + s2[1];
        pred = (ts1 > ts0) ? 1 : 0;
        if (g == 0 && tid == 0) {
            float m = fmaxf(ts0, ts1);
            float lse = m + log1pf(expf(-fabsf(ts0 - ts1)));
            float* op = out + ((size_t)b * TT + t) * 2;
            op[0] = ts0 - lse; op[1] = ts1 - lse;
        }
    }

    if (kq == 0) {
        sh[(size_t)b * HH + jglob] = hreg;
        sc[(size_t)b * HH + jglob] = creg;
    }
    if (g == 0 && tid == 0) sp[b] = pred;
}

// ---------------------------------------------------------------------------
extern "C" void kernel_launch(void* const* d_in, const int* in_sizes, int n_in,
                              void* d_out, int out_size, void* d_ws, size_t ws_size,
                              hipStream_t stream) {
    (void)in_sizes; (void)n_in; (void)out_size;
    const float* sents = (const float*)d_in[0];
    const float* mask  = (const float*)d_in[1];
    const float* Wih   = (const float*)d_in[2];
    const float* Whh   = (const float*)d_in[3];
    const float* bih   = (const float*)d_in[4];
    const float* bhh   = (const float*)d_in[5];
    const float* Waff  = (const float*)d_in[6];
    const float* baff  = (const float*)d_in[7];
    const float* tag   = (const float*)d_in[8];
    float* out = (float*)d_out;

    const size_t fixed = (size_t)BB * HH * 4 * 2    // sh, sc
                       + BB * 4                      // sp
                       + BB * 4 * 4                  // flg
                       + (size_t)2 * BB * 4 * 64 * 4 // hbox
                       + (size_t)2 * BB * 4 * 2 * 4  // sbox
                       + 4096;                       // slack
    int Tc = 8;
    const int cands[7] = {512, 256, 128, 64, 32, 16, 8};
    for (int i = 0; i < 7; ++i) {
        size_t need = (size_t)cands[i] * BB * NG * 4
                    + (size_t)cands[i] * BB * 2 * 4
                    + fixed;
        if (need <= ws_size) { Tc = cands[i]; break; }
    }

    char* wsp = (char*)d_ws;
    float* gpre = (float*)wsp; wsp += (size_t)Tc * BB * NG * 4;
    float* shiw = (float*)wsp; wsp += (size_t)Tc * BB * 2 * 4;
    float* shst = (float*)wsp; wsp += (size_t)BB * HH * 4;
    float* scst = (float*)wsp; wsp += (size_t)BB * HH * 4;
    int*   spst = (int*)wsp;   wsp += BB * 4;
    int*   flg  = (int*)wsp;   wsp += BB * 4 * 4;
    float* hbox = (float*)wsp; wsp += (size_t)2 * BB * 4 * 64 * 4;
    float* sbox = (float*)wsp;

    kinit<<<1, 256, 0, stream>>>(flg);

    const int nch = TT / Tc;
    for (int c = 0; c < nch; ++c) {
        const int t0 = c * Tc;
        kgemm<<<dim3(16, Tc), 256, 0, stream>>>(sents, Wih, bih, bhh, gpre, t0);
        kshi<<<dim3(Tc * 16), 256, 0, stream>>>(sents, Waff, baff, shiw, t0);
        krec2<<<dim3(256), 512, 0, stream>>>(gpre, shiw, Whh, mask, out,
                                             shst, scst, spst, flg, hbox, sbox,
                                             Wih, tag, Waff, t0, Tc, (c == 0) ? 1 : 0);
    }
}

// Round 3
// 2503.370 us; speedup vs baseline: 8.2388x; 8.2388x over previous
//
#include <hip/hip_runtime.h>
#include <cstdint>
#include <cstddef>

#define TT 512
#define BB 64
#define HH 256
#define NG 1024
#define DI 768
#define KY 32

__device__ __forceinline__ float sigf(float x) {
    return __fdividef(1.f, 1.f + __expf(-x));
}
__device__ __forceinline__ float tanhfast(float x) {
    return fmaf(2.f, sigf(2.f * x), -1.f);
}

// ---------------------------------------------------------------------------
// Kernel A: G_pre[tl][b][j] = sents[b][t0+tl][:] @ Wih[j][32:800]^T + bih[j]+bhh[j]
// ---------------------------------------------------------------------------
__global__ __launch_bounds__(256) void kgemm(
    const float* __restrict__ sents, const float* __restrict__ Wih,
    const float* __restrict__ bih, const float* __restrict__ bhh,
    float* __restrict__ gpre, int t0)
{
    __shared__ float As[16][68];
    __shared__ float Bs[16][64];
    const int tid = threadIdx.x;
    const int tl = blockIdx.y;
    const int jb = blockIdx.x * 64;
    const int tx = tid & 15, ty = tid >> 4;
    const int lr = tid >> 2, kq = tid & 3;

    float acc[4][4];
#pragma unroll
    for (int m = 0; m < 4; ++m)
#pragma unroll
        for (int n = 0; n < 4; ++n) acc[m][n] = 0.f;

    const float* arow = sents + ((size_t)lr * TT + t0 + tl) * DI;
    const float* brow = Wih + (size_t)(jb + lr) * 800 + KY;

    for (int k0 = 0; k0 < DI; k0 += 16) {
        float4 av = *(const float4*)(arow + k0 + kq * 4);
        float4 bv = *(const float4*)(brow + k0 + kq * 4);
        __syncthreads();
        As[kq * 4 + 0][lr] = av.x; As[kq * 4 + 1][lr] = av.y;
        As[kq * 4 + 2][lr] = av.z; As[kq * 4 + 3][lr] = av.w;
        Bs[kq * 4 + 0][lr] = bv.x; Bs[kq * 4 + 1][lr] = bv.y;
        Bs[kq * 4 + 2][lr] = bv.z; Bs[kq * 4 + 3][lr] = bv.w;
        __syncthreads();
#pragma unroll
        for (int k = 0; k < 16; ++k) {
            float4 a4 = *(const float4*)&As[k][ty * 4];
            float4 b4 = *(const float4*)&Bs[k][tx * 4];
            acc[0][0] = fmaf(a4.x, b4.x, acc[0][0]);
            acc[0][1] = fmaf(a4.x, b4.y, acc[0][1]);
            acc[0][2] = fmaf(a4.x, b4.z, acc[0][2]);
            acc[0][3] = fmaf(a4.x, b4.w, acc[0][3]);
            acc[1][0] = fmaf(a4.y, b4.x, acc[1][0]);
            acc[1][1] = fmaf(a4.y, b4.y, acc[1][1]);
            acc[1][2] = fmaf(a4.y, b4.z, acc[1][2]);
            acc[1][3] = fmaf(a4.y, b4.w, acc[1][3]);
            acc[2][0] = fmaf(a4.z, b4.x, acc[2][0]);
            acc[2][1] = fmaf(a4.z, b4.y, acc[2][1]);
            acc[2][2] = fmaf(a4.z, b4.z, acc[2][2]);
            acc[2][3] = fmaf(a4.z, b4.w, acc[2][3]);
            acc[3][0] = fmaf(a4.w, b4.x, acc[3][0]);
            acc[3][1] = fmaf(a4.w, b4.y, acc[3][1]);
            acc[3][2] = fmaf(a4.w, b4.z, acc[3][2]);
            acc[3][3] = fmaf(a4.w, b4.w, acc[3][3]);
        }
    }
    const int j0 = jb + tx * 4;
    float4 bias4;
    bias4.x = bih[j0 + 0] + bhh[j0 + 0];
    bias4.y = bih[j0 + 1] + bhh[j0 + 1];
    bias4.z = bih[j0 + 2] + bhh[j0 + 2];
    bias4.w = bih[j0 + 3] + bhh[j0 + 3];
#pragma unroll
    for (int m = 0; m < 4; ++m) {
        int row = ty * 4 + m;
        float4 o;
        o.x = acc[m][0] + bias4.x; o.y = acc[m][1] + bias4.y;
        o.z = acc[m][2] + bias4.z; o.w = acc[m][3] + bias4.w;
        *(float4*)(gpre + ((size_t)tl * BB + row) * NG + j0) = o;
    }
}

// ---------------------------------------------------------------------------
// Kernel S: SHi[tl][b][k] = sents[b][t0+tl][:] @ Waff[k][256:1024]^T + baff[k]
// ---------------------------------------------------------------------------
__global__ __launch_bounds__(256) void kshi(
    const float* __restrict__ sents, const float* __restrict__ Waff,
    const float* __restrict__ baff, float* __restrict__ shi, int t0)
{
    const int tid = threadIdx.x;
    const int lane = tid & 63;
    const int r = blockIdx.x * 4 + (tid >> 6);
    const int b = r & 63, tl = r >> 6;
    const float* hi = sents + ((size_t)b * TT + t0 + tl) * DI;
    float p0 = 0.f, p1 = 0.f;
#pragma unroll
    for (int kk = 0; kk < 12; ++kk) {
        int k = kk * 64 + lane;
        float x = hi[k];
        p0 = fmaf(x, Waff[HH + k], p0);
        p1 = fmaf(x, Waff[NG + HH + k], p1);
    }
#pragma unroll
    for (int off = 32; off >= 1; off >>= 1) {
        p0 += __shfl_xor(p0, off, 64);
        p1 += __shfl_xor(p1, off, 64);
    }
    if (lane == 0) {
        shi[(size_t)r * 2 + 0] = p0 + baff[0];
        shi[(size_t)r * 2 + 1] = p1 + baff[1];
    }
}

// ---------------------------------------------------------------------------
// init: zero the per-(b,g) step flags (ws is poisoned 0xAA before every run)
// ---------------------------------------------------------------------------
__global__ void kinit(int* __restrict__ flg) {
    flg[threadIdx.x] = 0;
}

// ---------------------------------------------------------------------------
// krec2: recurrence split 4 ways per batch element; RELAXED-only mailboxes.
// All cross-WG traffic uses relaxed agent-scope atomics (write-through to the
// coherent IF$, no buffer_inv / buffer_wbl2 cache maintenance). Producer-side
// ordering (data before flag) via `s_waitcnt vmcnt(0)` store-ack drain.
// ---------------------------------------------------------------------------
__global__ __launch_bounds__(512, 2) void krec2(
    const float* __restrict__ gpre,   // [Tc][64][1024]
    const float* __restrict__ shi,    // [Tc][64][2] (baff folded in)
    const float* __restrict__ Whh,    // [1024][256]
    const float* __restrict__ mask,   // [64][512]
    float* __restrict__ out,          // [64][512][2]
    float* __restrict__ sh, float* __restrict__ sc, int* __restrict__ sp,
    int* __restrict__ flg,            // [64][4]
    float* __restrict__ hbox,         // [2][64][4][64]
    float* __restrict__ sbox,         // [2][64][4][2]
    const float* __restrict__ Wih, const float* __restrict__ tag,
    const float* __restrict__ Waff,
    int t0, int Tc, int first)
{
    const int blk = blockIdx.x;
    const int g = blk >> 6, b = blk & 63;
    const int tid = threadIdx.x;
    const int w = tid >> 6, lane = tid & 63;
    const int jl = lane & 7, kq = lane >> 3;
    const int jh = w * 8 + jl;        // local h-dim 0..63
    const int jglob = g * 64 + jh;    // global h-dim

    __shared__ float hk[8 * 36];      // full h[256], K-octant-major, pad 36
    __shared__ float P[2][4][64];
    __shared__ float tg[2][KY];
    __shared__ float red[8][2];
    __shared__ float sred[4][2];

    // ---- Whh slice into registers: 32 float4 = 128 VGPRs ----
    float4 wreg[4][8];
#pragma unroll
    for (int gt = 0; gt < 4; ++gt) {
        const float4* src = (const float4*)(Whh + (size_t)(gt * HH + jglob) * HH + kq * 32);
#pragma unroll
        for (int kk = 0; kk < 8; ++kk) wreg[gt][kk] = src[kk];
    }
    const float waff0 = Waff[jglob];
    const float waff1 = Waff[NG + jglob];

    if (tid < 2 * KY) tg[tid >> 5][tid & 31] = tag[tid];
    __syncthreads();
    {
        int r = tid >> 8, rem = tid & 255, gt = rem >> 6, j2 = rem & 63;
        int row = gt * HH + g * 64 + j2;
        const float4* wr = (const float4*)(Wih + (size_t)row * 800);
        float s = 0.f;
#pragma unroll
        for (int kk = 0; kk < 8; ++kk) {
            float4 v = wr[kk];
            s = fmaf(v.x, tg[r][kk * 4 + 0], s);
            s = fmaf(v.y, tg[r][kk * 4 + 1], s);
            s = fmaf(v.z, tg[r][kk * 4 + 2], s);
            s = fmaf(v.w, tg[r][kk * 4 + 3], s);
        }
        P[r][gt][j2] = s;
    }

    float hreg, creg; int pred;
    if (first) {
        hreg = 0.f; creg = 0.f; pred = -1;
        if (tid < 72) ((float4*)hk)[tid] = make_float4(0.f, 0.f, 0.f, 0.f);
    } else {
        hreg = sh[(size_t)b * HH + jglob];
        creg = sc[(size_t)b * HH + jglob];
        pred = sp[b];
        if (tid < HH) hk[(tid >> 5) * 36 + (tid & 31)] = sh[(size_t)b * HH + tid];
    }
    __syncthreads();

    for (int tl = 0; tl < Tc; ++tl) {
        const int t = t0 + tl;
        const int p = t & 1;

        // prefetch (independent of h)
        const float* gp = gpre + ((size_t)tl * BB + b) * NG;
        float gp0 = gp[0 * HH + jglob];
        float gp1 = gp[1 * HH + jglob];
        float gp2 = gp[2 * HH + jglob];
        float gp3 = gp[3 * HH + jglob];
        float mi = mask[(size_t)b * TT + t];
        float pv0 = 0.f, pv1 = 0.f, pv2 = 0.f, pv3 = 0.f;
        if (pred >= 0) {
            pv0 = P[pred][0][jh]; pv1 = P[pred][1][jh];
            pv2 = P[pred][2][jh]; pv3 = P[pred][3][jh];
        }

        // ---- matvec: K-octant [32kq, 32kq+32) of 4 gate rows ----
        float a0 = 0.f, a1 = 0.f, a2 = 0.f, a3 = 0.f;
        const float4* h4 = (const float4*)(hk + kq * 36);
#pragma unroll
        for (int kk = 0; kk < 8; ++kk) {
            float4 hv = h4[kk];
            a0 = fmaf(wreg[0][kk].x, hv.x, a0); a0 = fmaf(wreg[0][kk].y, hv.y, a0);
            a0 = fmaf(wreg[0][kk].z, hv.z, a0); a0 = fmaf(wreg[0][kk].w, hv.w, a0);
            a1 = fmaf(wreg[1][kk].x, hv.x, a1); a1 = fmaf(wreg[1][kk].y, hv.y, a1);
            a1 = fmaf(wreg[1][kk].z, hv.z, a1); a1 = fmaf(wreg[1][kk].w, hv.w, a1);
            a2 = fmaf(wreg[2][kk].x, hv.x, a2); a2 = fmaf(wreg[2][kk].y, hv.y, a2);
            a2 = fmaf(wreg[2][kk].z, hv.z, a2); a2 = fmaf(wreg[2][kk].w, hv.w, a2);
            a3 = fmaf(wreg[3][kk].x, hv.x, a3); a3 = fmaf(wreg[3][kk].y, hv.y, a3);
            a3 = fmaf(wreg[3][kk].z, hv.z, a3); a3 = fmaf(wreg[3][kk].w, hv.w, a3);
        }
        a0 += __shfl_xor(a0, 8, 64); a0 += __shfl_xor(a0, 16, 64); a0 += __shfl_xor(a0, 32, 64);
        a1 += __shfl_xor(a1, 8, 64); a1 += __shfl_xor(a1, 16, 64); a1 += __shfl_xor(a1, 32, 64);
        a2 += __shfl_xor(a2, 8, 64); a2 += __shfl_xor(a2, 16, 64); a2 += __shfl_xor(a2, 32, 64);
        a3 += __shfl_xor(a3, 8, 64); a3 += __shfl_xor(a3, 16, 64); a3 += __shfl_xor(a3, 32, 64);

        float gi = a0 + gp0 + pv0;
        float gf = a1 + gp1 + pv1;
        float gg = a2 + gp2 + pv2;
        float go = a3 + gp3 + pv3;
        float ig = sigf(gi), fg = sigf(gf);
        float g2 = tanhfast(gg), og = sigf(go);
        float cn = fmaf(fg, creg, ig * g2);
        float hn = og * tanhfast(cn);
        float ho = hn * mi + hreg * (1.f - mi);
        float co = cn * mi + creg * (1.f - mi);

        __syncthreads();   // B0: everyone done reading hk this step

        if (kq == 0) {     // one writer per jh
            hk[(jglob >> 5) * 36 + (jglob & 31)] = ho;
            __hip_atomic_store(&hbox[((size_t)(p * BB + b) * 4 + g) * 64 + jh], ho,
                               __ATOMIC_RELAXED, __HIP_MEMORY_SCOPE_AGENT);
        }
        hreg = ho; creg = co;

        // score partial over this WG's 64 h-dims (pre-mask h_new)
        float p0 = (kq == 0) ? hn * waff0 : 0.f;
        float p1 = (kq == 0) ? hn * waff1 : 0.f;
#pragma unroll
        for (int off = 32; off >= 1; off >>= 1) {
            p0 += __shfl_xor(p0, off, 64);
            p1 += __shfl_xor(p1, off, 64);
        }
        if (lane == 0) { red[w][0] = p0; red[w][1] = p1; }

        // drain this wave's hbox stores to the coherence point (store-ack)
        asm volatile("s_waitcnt vmcnt(0)" ::: "memory");
        __syncthreads();   // B1: all hbox stores drained, red[] complete

        if (tid == 0) {
            float s0 = red[0][0], s1 = red[0][1];
#pragma unroll
            for (int wv = 1; wv < 8; ++wv) { s0 += red[wv][0]; s1 += red[wv][1]; }
            __hip_atomic_store(&sbox[((size_t)(p * BB + b) * 4 + g) * 2 + 0], s0,
                               __ATOMIC_RELAXED, __HIP_MEMORY_SCOPE_AGENT);
            __hip_atomic_store(&sbox[((size_t)(p * BB + b) * 4 + g) * 2 + 1], s1,
                               __ATOMIC_RELAXED, __HIP_MEMORY_SCOPE_AGENT);
            asm volatile("s_waitcnt vmcnt(0)" ::: "memory");
            __hip_atomic_store(&flg[b * 4 + g], t + 1,
                               __ATOMIC_RELAXED, __HIP_MEMORY_SCOPE_AGENT);
            sred[g][0] = s0; sred[g][1] = s1;
        }

        // loader waves poll their partner's flag themselves (same-address
        // lane loads coalesce to 1 request/wave), then pull the data.
        if (tid < 192) {
            int pg = (g + 1 + (tid >> 6)) & 3, j2 = tid & 63;
            const int* fp = &flg[b * 4 + pg];
            while (__hip_atomic_load(fp, __ATOMIC_RELAXED, __HIP_MEMORY_SCOPE_AGENT) < t + 1) {}
            float v = __hip_atomic_load(&hbox[((size_t)(p * BB + b) * 4 + pg) * 64 + j2],
                                        __ATOMIC_RELAXED, __HIP_MEMORY_SCOPE_AGENT);
            int kf = pg * 64 + j2;
            hk[(kf >> 5) * 36 + (kf & 31)] = v;
        } else if (tid < 198) {
            int i = tid - 192, pg = (g + 1 + (i >> 1)) & 3, c2 = i & 1;
            const int* fp = &flg[b * 4 + pg];
            while (__hip_atomic_load(fp, __ATOMIC_RELAXED, __HIP_MEMORY_SCOPE_AGENT) < t + 1) {}
            sred[pg][c2] = __hip_atomic_load(&sbox[((size_t)(p * BB + b) * 4 + pg) * 2 + c2],
                                             __ATOMIC_RELAXED, __HIP_MEMORY_SCOPE_AGENT);
        }
        __syncthreads();   // B3: hk + sred complete

        // identical total in all 4 WGs (fixed summation order, identical bits)
        float s0 = ((sred[0][0] + sred[1][0]) + sred[2][0]) + sred[3][0];
        float s1 = ((sred[0][1] + sred[1][1]) + sred[2][1]) + sred[3][1];
        const float* s2 = shi + ((size_t)tl * BB + b) * 2;
        float ts0 = s0 + s2[0], ts1 = s1 + s2[1];
        pred = (ts1 > ts0) ? 1 : 0;
        if (g == 0 && tid == 0) {
            float m = fmaxf(ts0, ts1);
            float lse = m + log1pf(expf(-fabsf(ts0 - ts1)));
            float* op = out + ((size_t)b * TT + t) * 2;
            op[0] = ts0 - lse; op[1] = ts1 - lse;
        }
    }

    if (kq == 0) {
        sh[(size_t)b * HH + jglob] = hreg;
        sc[(size_t)b * HH + jglob] = creg;
    }
    if (g == 0 && tid == 0) sp[b] = pred;
}

// ---------------------------------------------------------------------------
extern "C" void kernel_launch(void* const* d_in, const int* in_sizes, int n_in,
                              void* d_out, int out_size, void* d_ws, size_t ws_size,
                              hipStream_t stream) {
    (void)in_sizes; (void)n_in; (void)out_size;
    const float* sents = (const float*)d_in[0];
    const float* mask  = (const float*)d_in[1];
    const float* Wih   = (const float*)d_in[2];
    const float* Whh   = (const float*)d_in[3];
    const float* bih   = (const float*)d_in[4];
    const float* bhh   = (const float*)d_in[5];
    const float* Waff  = (const float*)d_in[6];
    const float* baff  = (const float*)d_in[7];
    const float* tag   = (const float*)d_in[8];
    float* out = (float*)d_out;

    const size_t fixed = (size_t)BB * HH * 4 * 2
                       + BB * 4
                       + BB * 4 * 4
                       + (size_t)2 * BB * 4 * 64 * 4
                       + (size_t)2 * BB * 4 * 2 * 4
                       + 4096;
    int Tc = 8;
    const int cands[7] = {512, 256, 128, 64, 32, 16, 8};
    for (int i = 0; i < 7; ++i) {
        size_t need = (size_t)cands[i] * BB * NG * 4
                    + (size_t)cands[i] * BB * 2 * 4
                    + fixed;
        if (need <= ws_size) { Tc = cands[i]; break; }
    }

    char* wsp = (char*)d_ws;
    float* gpre = (float*)wsp; wsp += (size_t)Tc * BB * NG * 4;
    float* shiw = (float*)wsp; wsp += (size_t)Tc * BB * 2 * 4;
    float* shst = (float*)wsp; wsp += (size_t)BB * HH * 4;
    float* scst = (float*)wsp; wsp += (size_t)BB * HH * 4;
    int*   spst = (int*)wsp;   wsp += BB * 4;
    int*   flg  = (int*)wsp;   wsp += BB * 4 * 4;
    float* hbox = (float*)wsp; wsp += (size_t)2 * BB * 4 * 64 * 4;
    float* sbox = (float*)wsp;

    kinit<<<1, 256, 0, stream>>>(flg);

    const int nch = TT / Tc;
    for (int c = 0; c < nch; ++c) {
        const int t0 = c * Tc;
        kgemm<<<dim3(16, Tc), 256, 0, stream>>>(sents, Wih, bih, bhh, gpre, t0);
        kshi<<<dim3(Tc * 16), 256, 0, stream>>>(sents, Waff, baff, shiw, t0);
        krec2<<<dim3(256), 512, 0, stream>>>(gpre, shiw, Whh, mask, out,
                                             shst, scst, spst, flg, hbox, sbox,
                                             Wih, tag, Waff, t0, Tc, (c == 0) ? 1 : 0);
    }
}

// Round 4
// 1892.780 us; speedup vs baseline: 10.8965x; 1.3226x over previous
//
#include <hip/hip_runtime.h>
#include <cstdint>
#include <cstddef>

#define TT 512
#define BB 64
#define HH 256
#define NG 1024
#define DI 768
#define KY 32

__device__ __forceinline__ float sigf(float x) {
    return __fdividef(1.f, 1.f + __expf(-x));
}
__device__ __forceinline__ float tanhfast(float x) {
    return fmaf(2.f, sigf(2.f * x), -1.f);
}

// ---------------------------------------------------------------------------
// Kernel A: G_pre[tl][b][j] = sents[b][t0+tl][:] @ Wih[j][32:800]^T + bih[j]+bhh[j]
// ---------------------------------------------------------------------------
__global__ __launch_bounds__(256) void kgemm(
    const float* __restrict__ sents, const float* __restrict__ Wih,
    const float* __restrict__ bih, const float* __restrict__ bhh,
    float* __restrict__ gpre, int t0)
{
    __shared__ float As[16][68];
    __shared__ float Bs[16][64];
    const int tid = threadIdx.x;
    const int tl = blockIdx.y;
    const int jb = blockIdx.x * 64;
    const int tx = tid & 15, ty = tid >> 4;
    const int lr = tid >> 2, kq = tid & 3;

    float acc[4][4];
#pragma unroll
    for (int m = 0; m < 4; ++m)
#pragma unroll
        for (int n = 0; n < 4; ++n) acc[m][n] = 0.f;

    const float* arow = sents + ((size_t)lr * TT + t0 + tl) * DI;
    const float* brow = Wih + (size_t)(jb + lr) * 800 + KY;

    for (int k0 = 0; k0 < DI; k0 += 16) {
        float4 av = *(const float4*)(arow + k0 + kq * 4);
        float4 bv = *(const float4*)(brow + k0 + kq * 4);
        __syncthreads();
        As[kq * 4 + 0][lr] = av.x; As[kq * 4 + 1][lr] = av.y;
        As[kq * 4 + 2][lr] = av.z; As[kq * 4 + 3][lr] = av.w;
        Bs[kq * 4 + 0][lr] = bv.x; Bs[kq * 4 + 1][lr] = bv.y;
        Bs[kq * 4 + 2][lr] = bv.z; Bs[kq * 4 + 3][lr] = bv.w;
        __syncthreads();
#pragma unroll
        for (int k = 0; k < 16; ++k) {
            float4 a4 = *(const float4*)&As[k][ty * 4];
            float4 b4 = *(const float4*)&Bs[k][tx * 4];
            acc[0][0] = fmaf(a4.x, b4.x, acc[0][0]);
            acc[0][1] = fmaf(a4.x, b4.y, acc[0][1]);
            acc[0][2] = fmaf(a4.x, b4.z, acc[0][2]);
            acc[0][3] = fmaf(a4.x, b4.w, acc[0][3]);
            acc[1][0] = fmaf(a4.y, b4.x, acc[1][0]);
            acc[1][1] = fmaf(a4.y, b4.y, acc[1][1]);
            acc[1][2] = fmaf(a4.y, b4.z, acc[1][2]);
            acc[1][3] = fmaf(a4.y, b4.w, acc[1][3]);
            acc[2][0] = fmaf(a4.z, b4.x, acc[2][0]);
            acc[2][1] = fmaf(a4.z, b4.y, acc[2][1]);
            acc[2][2] = fmaf(a4.z, b4.z, acc[2][2]);
            acc[2][3] = fmaf(a4.z, b4.w, acc[2][3]);
            acc[3][0] = fmaf(a4.w, b4.x, acc[3][0]);
            acc[3][1] = fmaf(a4.w, b4.y, acc[3][1]);
            acc[3][2] = fmaf(a4.w, b4.z, acc[3][2]);
            acc[3][3] = fmaf(a4.w, b4.w, acc[3][3]);
        }
    }
    const int j0 = jb + tx * 4;
    float4 bias4;
    bias4.x = bih[j0 + 0] + bhh[j0 + 0];
    bias4.y = bih[j0 + 1] + bhh[j0 + 1];
    bias4.z = bih[j0 + 2] + bhh[j0 + 2];
    bias4.w = bih[j0 + 3] + bhh[j0 + 3];
#pragma unroll
    for (int m = 0; m < 4; ++m) {
        int row = ty * 4 + m;
        float4 o;
        o.x = acc[m][0] + bias4.x; o.y = acc[m][1] + bias4.y;
        o.z = acc[m][2] + bias4.z; o.w = acc[m][3] + bias4.w;
        *(float4*)(gpre + ((size_t)tl * BB + row) * NG + j0) = o;
    }
}

// ---------------------------------------------------------------------------
// Kernel S: SHi[tl][b][k] = sents[b][t0+tl][:] @ Waff[k][256:1024]^T + baff[k]
// ---------------------------------------------------------------------------
__global__ __launch_bounds__(256) void kshi(
    const float* __restrict__ sents, const float* __restrict__ Waff,
    const float* __restrict__ baff, float* __restrict__ shi, int t0)
{
    const int tid = threadIdx.x;
    const int lane = tid & 63;
    const int r = blockIdx.x * 4 + (tid >> 6);
    const int b = r & 63, tl = r >> 6;
    const float* hi = sents + ((size_t)b * TT + t0 + tl) * DI;
    float p0 = 0.f, p1 = 0.f;
#pragma unroll
    for (int kk = 0; kk < 12; ++kk) {
        int k = kk * 64 + lane;
        float x = hi[k];
        p0 = fmaf(x, Waff[HH + k], p0);
        p1 = fmaf(x, Waff[NG + HH + k], p1);
    }
#pragma unroll
    for (int off = 32; off >= 1; off >>= 1) {
        p0 += __shfl_xor(p0, off, 64);
        p1 += __shfl_xor(p1, off, 64);
    }
    if (lane == 0) {
        shi[(size_t)r * 2 + 0] = p0 + baff[0];
        shi[(size_t)r * 2 + 1] = p1 + baff[1];
    }
}

// ---------------------------------------------------------------------------
// init: zero the packed mailbox words (ws is poisoned 0xAA before every run)
// hbox64: [2][64][4][64] uint64 -> 32768 words
// ---------------------------------------------------------------------------
__global__ void kinit(unsigned long long* __restrict__ hbox) {
    hbox[(size_t)blockIdx.x * 512 + threadIdx.x] = 0ull;
}

// ---------------------------------------------------------------------------
// krec3: recurrence split 4 ways per batch element; single-RT exchange.
// Data+validity packed in one 8-byte relaxed agent atomic:
//   word = (f32bits(hn) << 32) | (t+1)
// No fences, no flags, no drains. Double-buffered by step parity (exact-match
// counter is race-free: a WG can only publish t+3 into the same parity slot
// after partners consumed t+1, by the mutual dependency chain).
// Score/argmax recomputed per-WG from the full gathered hn vector in a fixed
// reduction order -> bit-identical pred in all 4 WGs, no score exchange.
// ---------------------------------------------------------------------------
__global__ __launch_bounds__(512, 1) void krec3(
    const float* __restrict__ gpre,   // [Tc][64][1024]
    const float* __restrict__ shi,    // [Tc][64][2] (baff folded in)
    const float* __restrict__ Whh,    // [1024][256]
    const float* __restrict__ mask,   // [64][512]
    float* __restrict__ out,          // [64][512][2]
    float* __restrict__ sh, float* __restrict__ sc, int* __restrict__ sp,
    unsigned long long* __restrict__ hbox,  // [2][64][4][64]
    const float* __restrict__ Wih, const float* __restrict__ tag,
    const float* __restrict__ Waff,
    int t0, int Tc, int first)
{
    const int blk = blockIdx.x;
    const int g = blk >> 6, b = blk & 63;
    const int tid = threadIdx.x;
    const int w = tid >> 6, lane = tid & 63;
    const int jl = lane & 7, kq = lane >> 3;
    const int jh = w * 8 + jl;        // local h-dim 0..63
    const int jglob = g * 64 + jh;    // global h-dim

    __shared__ float hk[8 * 36];      // h_out (masked), K-octant-major, pad 36
    __shared__ float hnS[HH];         // this step's pre-mask h_new, all 256 dims
    __shared__ float P[2][4][64];     // tag-feedback precompute for this slice
    __shared__ float tg[2][KY];
    __shared__ float red[8][2];

    // ---- Whh slice into registers: 32 float4 = 128 VGPRs ----
    float4 wreg[4][8];
#pragma unroll
    for (int gt = 0; gt < 4; ++gt) {
        const float4* src = (const float4*)(Whh + (size_t)(gt * HH + jglob) * HH + kq * 32);
#pragma unroll
        for (int kk = 0; kk < 8; ++kk) wreg[gt][kk] = src[kk];
    }

    // score role: this thread covers dim sdim for tag stag
    const int sdim = w * 32 + (lane & 31);
    const int stag = lane >> 5;
    const float waffR = Waff[(size_t)stag * NG + sdim];

    if (tid < 2 * KY) tg[tid >> 5][tid & 31] = tag[tid];
    __syncthreads();
    {   // P[r][gt][j2] = tag_em[r] @ Wih[gt*256 + 64g + j2][0:32]^T  (512 entries)
        int r = tid >> 8, rem = tid & 255, gt = rem >> 6, j2 = rem & 63;
        int row = gt * HH + g * 64 + j2;
        const float4* wr = (const float4*)(Wih + (size_t)row * 800);
        float s = 0.f;
#pragma unroll
        for (int kk = 0; kk < 8; ++kk) {
            float4 v = wr[kk];
            s = fmaf(v.x, tg[r][kk * 4 + 0], s);
            s = fmaf(v.y, tg[r][kk * 4 + 1], s);
            s = fmaf(v.z, tg[r][kk * 4 + 2], s);
            s = fmaf(v.w, tg[r][kk * 4 + 3], s);
        }
        P[r][gt][j2] = s;
    }

    float creg; int pred;
    if (first) {
        creg = 0.f; pred = -1;
        if (tid < 72) ((float4*)hk)[tid] = make_float4(0.f, 0.f, 0.f, 0.f);
    } else {
        creg = sc[(size_t)b * HH + jglob];
        pred = sp[b];
        if (tid < HH) hk[(tid >> 5) * 36 + (tid & 31)] = sh[(size_t)b * HH + tid];
    }
    __syncthreads();

    for (int tl = 0; tl < Tc; ++tl) {
        const int t = t0 + tl;
        const int p = t & 1;

        // prefetch (independent of h)
        const float* gp = gpre + ((size_t)tl * BB + b) * NG;
        float gp0 = gp[0 * HH + jglob];
        float gp1 = gp[1 * HH + jglob];
        float gp2 = gp[2 * HH + jglob];
        float gp3 = gp[3 * HH + jglob];
        float mi = mask[(size_t)b * TT + t];
        const float* s2 = shi + ((size_t)tl * BB + b) * 2;
        float s2v0 = s2[0], s2v1 = s2[1];
        float pv0 = 0.f, pv1 = 0.f, pv2 = 0.f, pv3 = 0.f;
        if (pred >= 0) {
            pv0 = P[pred][0][jh]; pv1 = P[pred][1][jh];
            pv2 = P[pred][2][jh]; pv3 = P[pred][3][jh];
        }

        // ---- matvec: K-octant [32kq, 32kq+32) of 4 gate rows ----
        float a0 = 0.f, a1 = 0.f, a2 = 0.f, a3 = 0.f;
        const float4* h4 = (const float4*)(hk + kq * 36);
#pragma unroll
        for (int kk = 0; kk < 8; ++kk) {
            float4 hv = h4[kk];
            a0 = fmaf(wreg[0][kk].x, hv.x, a0); a0 = fmaf(wreg[0][kk].y, hv.y, a0);
            a0 = fmaf(wreg[0][kk].z, hv.z, a0); a0 = fmaf(wreg[0][kk].w, hv.w, a0);
            a1 = fmaf(wreg[1][kk].x, hv.x, a1); a1 = fmaf(wreg[1][kk].y, hv.y, a1);
            a1 = fmaf(wreg[1][kk].z, hv.z, a1); a1 = fmaf(wreg[1][kk].w, hv.w, a1);
            a2 = fmaf(wreg[2][kk].x, hv.x, a2); a2 = fmaf(wreg[2][kk].y, hv.y, a2);
            a2 = fmaf(wreg[2][kk].z, hv.z, a2); a2 = fmaf(wreg[2][kk].w, hv.w, a2);
            a3 = fmaf(wreg[3][kk].x, hv.x, a3); a3 = fmaf(wreg[3][kk].y, hv.y, a3);
            a3 = fmaf(wreg[3][kk].z, hv.z, a3); a3 = fmaf(wreg[3][kk].w, hv.w, a3);
        }
        a0 += __shfl_xor(a0, 8, 64); a0 += __shfl_xor(a0, 16, 64); a0 += __shfl_xor(a0, 32, 64);
        a1 += __shfl_xor(a1, 8, 64); a1 += __shfl_xor(a1, 16, 64); a1 += __shfl_xor(a1, 32, 64);
        a2 += __shfl_xor(a2, 8, 64); a2 += __shfl_xor(a2, 16, 64); a2 += __shfl_xor(a2, 32, 64);
        a3 += __shfl_xor(a3, 8, 64); a3 += __shfl_xor(a3, 16, 64); a3 += __shfl_xor(a3, 32, 64);

        float gi = a0 + gp0 + pv0;
        float gf = a1 + gp1 + pv1;
        float gg = a2 + gp2 + pv2;
        float go = a3 + gp3 + pv3;
        float ig = sigf(gi), fg = sigf(gf);
        float g2 = tanhfast(gg), og = sigf(go);
        float cn = fmaf(fg, creg, ig * g2);
        float hn = og * tanhfast(cn);
        creg = cn * mi + creg * (1.f - mi);   // c_out (identical in the 8 kq-replicas)

        // ---- publish own slice: one packed 8B word per dim, no fence ----
        if (kq == 0) {
            unsigned long long wd =
                ((unsigned long long)__float_as_uint(hn) << 32) | (unsigned)(t + 1);
            __hip_atomic_store(&hbox[((size_t)(p * BB + b) * 4 + g) * 64 + jh], wd,
                               __ATOMIC_RELAXED, __HIP_MEMORY_SCOPE_AGENT);
            hnS[jglob] = hn;
        }
        // ---- gather partner slices: waves 0..2, one word per thread ----
        if (tid < 192) {
            int pg = (g + 1 + (tid >> 6)) & 3, j2 = tid & 63;
            const unsigned long long* wp = &hbox[((size_t)(p * BB + b) * 4 + pg) * 64 + j2];
            unsigned long long wv;
            do {
                wv = __hip_atomic_load(wp, __ATOMIC_RELAXED, __HIP_MEMORY_SCOPE_AGENT);
            } while ((unsigned)wv != (unsigned)(t + 1));
            hnS[pg * 64 + j2] = __uint_as_float((unsigned)(wv >> 32));
        }
        __syncthreads();   // B3: hnS complete; all hk reads of this step done

        // ---- h_out update for all 256 dims ----
        if (tid < HH) {
            int idx = (tid >> 5) * 36 + (tid & 31);
            float hold = hk[idx];
            hk[idx] = hnS[tid] * mi + hold * (1.f - mi);
        }
        // ---- full score recompute (fixed order, bit-identical in all WGs) ----
        float prod = hnS[sdim] * waffR;
        prod += __shfl_xor(prod, 1, 64);
        prod += __shfl_xor(prod, 2, 64);
        prod += __shfl_xor(prod, 4, 64);
        prod += __shfl_xor(prod, 8, 64);
        prod += __shfl_xor(prod, 16, 64);
        if ((lane & 31) == 0) red[w][stag] = prod;
        __syncthreads();   // B4: red + hk complete

        float s0 = red[0][0];
        s0 += red[1][0]; s0 += red[2][0]; s0 += red[3][0];
        s0 += red[4][0]; s0 += red[5][0]; s0 += red[6][0]; s0 += red[7][0];
        float s1 = red[0][1];
        s1 += red[1][1]; s1 += red[2][1]; s1 += red[3][1];
        s1 += red[4][1]; s1 += red[5][1]; s1 += red[6][1]; s1 += red[7][1];
        float ts0 = s0 + s2v0, ts1 = s1 + s2v1;
        pred = (ts1 > ts0) ? 1 : 0;
        if (g == 0 && tid == 0) {
            float m = fmaxf(ts0, ts1);
            float lse = m + log1pf(expf(-fabsf(ts0 - ts1)));
            float* op = out + ((size_t)b * TT + t) * 2;
            op[0] = ts0 - lse; op[1] = ts1 - lse;
        }
    }

    if (kq == 0) {
        sh[(size_t)b * HH + jglob] = hk[(jglob >> 5) * 36 + (jglob & 31)];
        sc[(size_t)b * HH + jglob] = creg;
    }
    if (g == 0 && tid == 0) sp[b] = pred;
}

// ---------------------------------------------------------------------------
extern "C" void kernel_launch(void* const* d_in, const int* in_sizes, int n_in,
                              void* d_out, int out_size, void* d_ws, size_t ws_size,
                              hipStream_t stream) {
    (void)in_sizes; (void)n_in; (void)out_size;
    const float* sents = (const float*)d_in[0];
    const float* mask  = (const float*)d_in[1];
    const float* Wih   = (const float*)d_in[2];
    const float* Whh   = (const float*)d_in[3];
    const float* bih   = (const float*)d_in[4];
    const float* bhh   = (const float*)d_in[5];
    const float* Waff  = (const float*)d_in[6];
    const float* baff  = (const float*)d_in[7];
    const float* tag   = (const float*)d_in[8];
    float* out = (float*)d_out;

    const size_t fixed = (size_t)BB * HH * 4 * 2          // sh, sc
                       + BB * 4                            // sp
                       + (size_t)2 * BB * 4 * 64 * 8      // hbox (uint64)
                       + 4096;                             // slack
    int Tc = 8;
    const int cands[7] = {512, 256, 128, 64, 32, 16, 8};
    for (int i = 0; i < 7; ++i) {
        size_t need = (size_t)cands[i] * BB * NG * 4
                    + (size_t)cands[i] * BB * 2 * 4
                    + fixed;
        if (need <= ws_size) { Tc = cands[i]; break; }
    }

    char* wsp = (char*)d_ws;
    float* gpre = (float*)wsp; wsp += (size_t)Tc * BB * NG * 4;
    float* shiw = (float*)wsp; wsp += (size_t)Tc * BB * 2 * 4;
    float* shst = (float*)wsp; wsp += (size_t)BB * HH * 4;
    float* scst = (float*)wsp; wsp += (size_t)BB * HH * 4;
    int*   spst = (int*)wsp;   wsp += BB * 4;
    unsigned long long* hbox = (unsigned long long*)wsp;

    kinit<<<dim3(64), 512, 0, stream>>>(hbox);   // 32768 words

    const int nch = TT / Tc;
    for (int c = 0; c < nch; ++c) {
        const int t0 = c * Tc;
        kgemm<<<dim3(16, Tc), 256, 0, stream>>>(sents, Wih, bih, bhh, gpre, t0);
        kshi<<<dim3(Tc * 16), 256, 0, stream>>>(sents, Waff, baff, shiw, t0);
        krec3<<<dim3(256), 512, 0, stream>>>(gpre, shiw, Whh, mask, out,
                                             shst, scst, spst, hbox,
                                             Wih, tag, Waff, t0, Tc, (c == 0) ? 1 : 0);
    }
}

// Round 5
// 1436.132 us; speedup vs baseline: 14.3613x; 1.3180x over previous
//
#include <hip/hip_runtime.h>
#include <cstdint>
#include <cstddef>

#define TT 512
#define BB 64
#define HH 256
#define NG 1024
#define DI 768
#define KY 32

#define LDP 56   // LDS row pitch (bf16 elems): 112B = 16B-aligned rows, 2-way-only bank aliasing

typedef __attribute__((ext_vector_type(8))) short bfrag_t;
typedef __attribute__((ext_vector_type(4))) float f4_t;

__device__ __forceinline__ float sigf(float x) {
    return __fdividef(1.f, 1.f + __expf(-x));
}
__device__ __forceinline__ float tanhfast(float x) {
    return fmaf(2.f, sigf(2.f * x), -1.f);
}
__device__ __forceinline__ unsigned short bf_hi(float x) {
    return (unsigned short)(__float_as_uint(x) >> 16);        // truncate to bf16
}
__device__ __forceinline__ float bf_hi_f(float x) {
    return __uint_as_float(__float_as_uint(x) & 0xffff0000u); // exact hi part as f32
}

// ---------------------------------------------------------------------------
// kgemm2: G_pre = A @ B^T + bias via split-bf16 MFMA (3 products: hh+hl+lh,
// error ~2^-16 relative — trajectory-safe).
//   A[m][k] = sents[b][t0+tl][k],  m = tl*64+b, k in [0,768)
//   B[n][k] = Wih[n][32+k],        n in [0,1024)
// 128x128 tile / 256 thr (4 waves 2x2, 4x4 16x16x32 frags each), BK=32.
// grid (8 = N-tiles, M/128); consecutive blockIdx.x share the A-slab (L2/IF$).
// ---------------------------------------------------------------------------
__global__ __launch_bounds__(256) void kgemm2(
    const float* __restrict__ sents, const float* __restrict__ Wih,
    const float* __restrict__ bih, const float* __restrict__ bhh,
    float* __restrict__ gpre, int t0)
{
    __shared__ unsigned short Ah[128 * LDP], Al[128 * LDP];
    __shared__ unsigned short Bh[128 * LDP], Bl[128 * LDP];

    const int tid = threadIdx.x;
    const int nb = blockIdx.x;            // N tile 0..7
    const int mb = blockIdx.y;            // M tile
    const int wv = tid >> 6, lane = tid & 63;
    const int wm = (wv >> 1) * 64, wn = (wv & 1) * 64;  // wave quadrant
    const int fl = lane & 15, quad = lane >> 4;

    f4_t acc[4][4];
#pragma unroll
    for (int mi = 0; mi < 4; ++mi)
#pragma unroll
        for (int ni = 0; ni < 4; ++ni) acc[mi][ni] = (f4_t)0.f;

    // staging role: row sr (0..127), k-offset sk (0 or 16)
    const int sr = tid >> 1, sk = (tid & 1) * 16;
    const int gr = mb * 128 + sr;                       // global A row
    const float* aptr = sents + ((size_t)(gr & 63) * TT + t0 + (gr >> 6)) * DI + sk;
    const float* bptr = Wih + (size_t)(nb * 128 + sr) * 800 + KY + sk;

    for (int k0 = 0; k0 < DI; k0 += 32) {
        float4 av[4], bv[4];
#pragma unroll
        for (int i = 0; i < 4; ++i) {
            av[i] = *(const float4*)(aptr + k0 + i * 4);
            bv[i] = *(const float4*)(bptr + k0 + i * 4);
        }
        __syncthreads();   // previous compute done reading LDS
#pragma unroll
        for (int i = 0; i < 4; ++i) {
            ushort4 h4, l4;
            h4.x = bf_hi(av[i].x); l4.x = bf_hi(av[i].x - bf_hi_f(av[i].x));
            h4.y = bf_hi(av[i].y); l4.y = bf_hi(av[i].y - bf_hi_f(av[i].y));
            h4.z = bf_hi(av[i].z); l4.z = bf_hi(av[i].z - bf_hi_f(av[i].z));
            h4.w = bf_hi(av[i].w); l4.w = bf_hi(av[i].w - bf_hi_f(av[i].w));
            *(ushort4*)&Ah[sr * LDP + sk + i * 4] = h4;
            *(ushort4*)&Al[sr * LDP + sk + i * 4] = l4;
            h4.x = bf_hi(bv[i].x); l4.x = bf_hi(bv[i].x - bf_hi_f(bv[i].x));
            h4.y = bf_hi(bv[i].y); l4.y = bf_hi(bv[i].y - bf_hi_f(bv[i].y));
            h4.z = bf_hi(bv[i].z); l4.z = bf_hi(bv[i].z - bf_hi_f(bv[i].z));
            h4.w = bf_hi(bv[i].w); l4.w = bf_hi(bv[i].w - bf_hi_f(bv[i].w));
            *(ushort4*)&Bh[sr * LDP + sk + i * 4] = h4;
            *(ushort4*)&Bl[sr * LDP + sk + i * 4] = l4;
        }
        __syncthreads();   // tile staged

        bfrag_t ah[4], al2[4], bh[4], bl2[4];
#pragma unroll
        for (int mi = 0; mi < 4; ++mi) {
            int row = wm + mi * 16 + fl;
            ah[mi]  = *(const bfrag_t*)&Ah[row * LDP + quad * 8];
            al2[mi] = *(const bfrag_t*)&Al[row * LDP + quad * 8];
        }
#pragma unroll
        for (int ni = 0; ni < 4; ++ni) {
            int col = wn + ni * 16 + fl;
            bh[ni]  = *(const bfrag_t*)&Bh[col * LDP + quad * 8];
            bl2[ni] = *(const bfrag_t*)&Bl[col * LDP + quad * 8];
        }
#pragma unroll
        for (int mi = 0; mi < 4; ++mi)
#pragma unroll
            for (int ni = 0; ni < 4; ++ni) {
                acc[mi][ni] = __builtin_amdgcn_mfma_f32_16x16x32_bf16(
                    ah[mi], bh[ni], acc[mi][ni], 0, 0, 0);
                acc[mi][ni] = __builtin_amdgcn_mfma_f32_16x16x32_bf16(
                    ah[mi], bl2[ni], acc[mi][ni], 0, 0, 0);
                acc[mi][ni] = __builtin_amdgcn_mfma_f32_16x16x32_bf16(
                    al2[mi], bh[ni], acc[mi][ni], 0, 0, 0);
            }
    }

    // epilogue: C/D layout col=lane&15, row=quad*4+reg (m89-verified)
#pragma unroll
    for (int ni = 0; ni < 4; ++ni) {
        int gcol = nb * 128 + wn + ni * 16 + fl;
        float bias = bih[gcol] + bhh[gcol];
#pragma unroll
        for (int mi = 0; mi < 4; ++mi) {
            int grow = mb * 128 + wm + mi * 16 + quad * 4;
#pragma unroll
            for (int r = 0; r < 4; ++r)
                gpre[(size_t)(grow + r) * NG + gcol] = acc[mi][ni][r] + bias;
        }
    }
}

// ---------------------------------------------------------------------------
// Kernel S: SHi[tl][b][k] = sents[b][t0+tl][:] @ Waff[k][256:1024]^T + baff[k]
// ---------------------------------------------------------------------------
__global__ __launch_bounds__(256) void kshi(
    const float* __restrict__ sents, const float* __restrict__ Waff,
    const float* __restrict__ baff, float* __restrict__ shi, int t0)
{
    const int tid = threadIdx.x;
    const int lane = tid & 63;
    const int r = blockIdx.x * 4 + (tid >> 6);
    const int b = r & 63, tl = r >> 6;
    const float* hi = sents + ((size_t)b * TT + t0 + tl) * DI;
    float p0 = 0.f, p1 = 0.f;
#pragma unroll
    for (int kk = 0; kk < 12; ++kk) {
        int k = kk * 64 + lane;
        float x = hi[k];
        p0 = fmaf(x, Waff[HH + k], p0);
        p1 = fmaf(x, Waff[NG + HH + k], p1);
    }
#pragma unroll
    for (int off = 32; off >= 1; off >>= 1) {
        p0 += __shfl_xor(p0, off, 64);
        p1 += __shfl_xor(p1, off, 64);
    }
    if (lane == 0) {
        shi[(size_t)r * 2 + 0] = p0 + baff[0];
        shi[(size_t)r * 2 + 1] = p1 + baff[1];
    }
}

// ---------------------------------------------------------------------------
// init: zero the packed mailbox words (ws is poisoned 0xAA before every run)
// ---------------------------------------------------------------------------
__global__ void kinit(unsigned long long* __restrict__ hbox) {
    hbox[(size_t)blockIdx.x * 512 + threadIdx.x] = 0ull;
}

// ---------------------------------------------------------------------------
// krec3: recurrence split 4 ways per batch element; single-RT packed exchange
// (word = f32bits(hn)<<32 | t+1, relaxed agent atomics, parity double-buffer).
// This round: next-step gpre/mask/shi prefetched into registers BEFORE the
// poll loop, hiding HBM latency under the mailbox wait.
// ---------------------------------------------------------------------------
__global__ __launch_bounds__(512, 1) void krec3(
    const float* __restrict__ gpre,   // [Tc][64][1024]
    const float* __restrict__ shi,    // [Tc][64][2]
    const float* __restrict__ Whh,    // [1024][256]
    const float* __restrict__ mask,   // [64][512]
    float* __restrict__ out,          // [64][512][2]
    float* __restrict__ sh, float* __restrict__ sc, int* __restrict__ sp,
    unsigned long long* __restrict__ hbox,  // [2][64][4][64]
    const float* __restrict__ Wih, const float* __restrict__ tag,
    const float* __restrict__ Waff,
    int t0, int Tc, int first)
{
    const int blk = blockIdx.x;
    const int g = blk >> 6, b = blk & 63;
    const int tid = threadIdx.x;
    const int w = tid >> 6, lane = tid & 63;
    const int jl = lane & 7, kq = lane >> 3;
    const int jh = w * 8 + jl;
    const int jglob = g * 64 + jh;

    __shared__ float hk[8 * 36];
    __shared__ float hnS[HH];
    __shared__ float P[2][4][64];
    __shared__ float tg[2][KY];
    __shared__ float red[8][2];

    float4 wreg[4][8];
#pragma unroll
    for (int gt = 0; gt < 4; ++gt) {
        const float4* src = (const float4*)(Whh + (size_t)(gt * HH + jglob) * HH + kq * 32);
#pragma unroll
        for (int kk = 0; kk < 8; ++kk) wreg[gt][kk] = src[kk];
    }

    const int sdim = w * 32 + (lane & 31);
    const int stag = lane >> 5;
    const float waffR = Waff[(size_t)stag * NG + sdim];

    if (tid < 2 * KY) tg[tid >> 5][tid & 31] = tag[tid];
    __syncthreads();
    {
        int r = tid >> 8, rem = tid & 255, gt = rem >> 6, j2 = rem & 63;
        int row = gt * HH + g * 64 + j2;
        const float4* wr = (const float4*)(Wih + (size_t)row * 800);
        float s = 0.f;
#pragma unroll
        for (int kk = 0; kk < 8; ++kk) {
            float4 v = wr[kk];
            s = fmaf(v.x, tg[r][kk * 4 + 0], s);
            s = fmaf(v.y, tg[r][kk * 4 + 1], s);
            s = fmaf(v.z, tg[r][kk * 4 + 2], s);
            s = fmaf(v.w, tg[r][kk * 4 + 3], s);
        }
        P[r][gt][j2] = s;
    }

    float creg; int pred;
    if (first) {
        creg = 0.f; pred = -1;
        if (tid < 72) ((float4*)hk)[tid] = make_float4(0.f, 0.f, 0.f, 0.f);
    } else {
        creg = sc[(size_t)b * HH + jglob];
        pred = sp[b];
        if (tid < HH) hk[(tid >> 5) * 36 + (tid & 31)] = sh[(size_t)b * HH + tid];
    }
    __syncthreads();

    // current-step operand registers (prefetched)
    float cgp0, cgp1, cgp2, cgp3, cmi, cs0, cs1;
    {
        const float* gp = gpre + ((size_t)0 * BB + b) * NG;
        cgp0 = gp[0 * HH + jglob]; cgp1 = gp[1 * HH + jglob];
        cgp2 = gp[2 * HH + jglob]; cgp3 = gp[3 * HH + jglob];
        cmi = mask[(size_t)b * TT + t0];
        const float* s2 = shi + ((size_t)0 * BB + b) * 2;
        cs0 = s2[0]; cs1 = s2[1];
    }

    for (int tl = 0; tl < Tc; ++tl) {
        const int t = t0 + tl;
        const int p = t & 1;

        float pv0 = 0.f, pv1 = 0.f, pv2 = 0.f, pv3 = 0.f;
        if (pred >= 0) {
            pv0 = P[pred][0][jh]; pv1 = P[pred][1][jh];
            pv2 = P[pred][2][jh]; pv3 = P[pred][3][jh];
        }

        float a0 = 0.f, a1 = 0.f, a2 = 0.f, a3 = 0.f;
        const float4* h4 = (const float4*)(hk + kq * 36);
#pragma unroll
        for (int kk = 0; kk < 8; ++kk) {
            float4 hv = h4[kk];
            a0 = fmaf(wreg[0][kk].x, hv.x, a0); a0 = fmaf(wreg[0][kk].y, hv.y, a0);
            a0 = fmaf(wreg[0][kk].z, hv.z, a0); a0 = fmaf(wreg[0][kk].w, hv.w, a0);
            a1 = fmaf(wreg[1][kk].x, hv.x, a1); a1 = fmaf(wreg[1][kk].y, hv.y, a1);
            a1 = fmaf(wreg[1][kk].z, hv.z, a1); a1 = fmaf(wreg[1][kk].w, hv.w, a1);
            a2 = fmaf(wreg[2][kk].x, hv.x, a2); a2 = fmaf(wreg[2][kk].y, hv.y, a2);
            a2 = fmaf(wreg[2][kk].z, hv.z, a2); a2 = fmaf(wreg[2][kk].w, hv.w, a2);
            a3 = fmaf(wreg[3][kk].x, hv.x, a3); a3 = fmaf(wreg[3][kk].y, hv.y, a3);
            a3 = fmaf(wreg[3][kk].z, hv.z, a3); a3 = fmaf(wreg[3][kk].w, hv.w, a3);
        }
        a0 += __shfl_xor(a0, 8, 64); a0 += __shfl_xor(a0, 16, 64); a0 += __shfl_xor(a0, 32, 64);
        a1 += __shfl_xor(a1, 8, 64); a1 += __shfl_xor(a1, 16, 64); a1 += __shfl_xor(a1, 32, 64);
        a2 += __shfl_xor(a2, 8, 64); a2 += __shfl_xor(a2, 16, 64); a2 += __shfl_xor(a2, 32, 64);
        a3 += __shfl_xor(a3, 8, 64); a3 += __shfl_xor(a3, 16, 64); a3 += __shfl_xor(a3, 32, 64);

        float gi = a0 + cgp0 + pv0;
        float gf = a1 + cgp1 + pv1;
        float gg = a2 + cgp2 + pv2;
        float go = a3 + cgp3 + pv3;
        float ig = sigf(gi), fg = sigf(gf);
        float g2 = tanhfast(gg), og = sigf(go);
        float cn = fmaf(fg, creg, ig * g2);
        float hn = og * tanhfast(cn);
        float mi = cmi;
        float s2v0 = cs0, s2v1 = cs1;
        creg = cn * mi + creg * (1.f - mi);

        // publish own slice (one packed 8B word per dim, no fence)
        if (kq == 0) {
            unsigned long long wd =
                ((unsigned long long)__float_as_uint(hn) << 32) | (unsigned)(t + 1);
            __hip_atomic_store(&hbox[((size_t)(p * BB + b) * 4 + g) * 64 + jh], wd,
                               __ATOMIC_RELAXED, __HIP_MEMORY_SCOPE_AGENT);
            hnS[jglob] = hn;
        }

        // ---- prefetch next step's operands NOW (hidden under the poll) ----
        if (tl + 1 < Tc) {
            const float* gp2 = gpre + ((size_t)(tl + 1) * BB + b) * NG;
            cgp0 = gp2[0 * HH + jglob]; cgp1 = gp2[1 * HH + jglob];
            cgp2 = gp2[2 * HH + jglob]; cgp3 = gp2[3 * HH + jglob];
            cmi = mask[(size_t)b * TT + t + 1];
            const float* s2n = shi + ((size_t)(tl + 1) * BB + b) * 2;
            cs0 = s2n[0]; cs1 = s2n[1];
        }

        // gather partner slices
        if (tid < 192) {
            int pg = (g + 1 + (tid >> 6)) & 3, j2 = tid & 63;
            const unsigned long long* wp = &hbox[((size_t)(p * BB + b) * 4 + pg) * 64 + j2];
            unsigned long long wv;
            do {
                wv = __hip_atomic_load(wp, __ATOMIC_RELAXED, __HIP_MEMORY_SCOPE_AGENT);
            } while ((unsigned)wv != (unsigned)(t + 1));
            hnS[pg * 64 + j2] = __uint_as_float((unsigned)(wv >> 32));
        }
        __syncthreads();   // B3: hnS complete; hk reads of this step done

        if (tid < HH) {
            int idx = (tid >> 5) * 36 + (tid & 31);
            float hold = hk[idx];
            hk[idx] = hnS[tid] * mi + hold * (1.f - mi);
        }
        float prod = hnS[sdim] * waffR;
        prod += __shfl_xor(prod, 1, 64);
        prod += __shfl_xor(prod, 2, 64);
        prod += __shfl_xor(prod, 4, 64);
        prod += __shfl_xor(prod, 8, 64);
        prod += __shfl_xor(prod, 16, 64);
        if ((lane & 31) == 0) red[w][stag] = prod;
        __syncthreads();   // B4: red + hk complete

        float s0 = red[0][0];
        s0 += red[1][0]; s0 += red[2][0]; s0 += red[3][0];
        s0 += red[4][0]; s0 += red[5][0]; s0 += red[6][0]; s0 += red[7][0];
        float s1 = red[0][1];
        s1 += red[1][1]; s1 += red[2][1]; s1 += red[3][1];
        s1 += red[4][1]; s1 += red[5][1]; s1 += red[6][1]; s1 += red[7][1];
        float ts0 = s0 + s2v0, ts1 = s1 + s2v1;
        pred = (ts1 > ts0) ? 1 : 0;
        if (g == 0 && tid == 0) {
            float m = fmaxf(ts0, ts1);
            float lse = m + log1pf(expf(-fabsf(ts0 - ts1)));
            float* op = out + ((size_t)b * TT + t) * 2;
            op[0] = ts0 - lse; op[1] = ts1 - lse;
        }
    }

    if (kq == 0) {
        sh[(size_t)b * HH + jglob] = hk[(jglob >> 5) * 36 + (jglob & 31)];
        sc[(size_t)b * HH + jglob] = creg;
    }
    if (g == 0 && tid == 0) sp[b] = pred;
}

// ---------------------------------------------------------------------------
extern "C" void kernel_launch(void* const* d_in, const int* in_sizes, int n_in,
                              void* d_out, int out_size, void* d_ws, size_t ws_size,
                              hipStream_t stream) {
    (void)in_sizes; (void)n_in; (void)out_size;
    const float* sents = (const float*)d_in[0];
    const float* mask  = (const float*)d_in[1];
    const float* Wih   = (const float*)d_in[2];
    const float* Whh   = (const float*)d_in[3];
    const float* bih   = (const float*)d_in[4];
    const float* bhh   = (const float*)d_in[5];
    const float* Waff  = (const float*)d_in[6];
    const float* baff  = (const float*)d_in[7];
    const float* tag   = (const float*)d_in[8];
    float* out = (float*)d_out;

    const size_t fixed = (size_t)BB * HH * 4 * 2
                       + BB * 4
                       + (size_t)2 * BB * 4 * 64 * 8
                       + 4096;
    int Tc = 8;
    const int cands[7] = {512, 256, 128, 64, 32, 16, 8};
    for (int i = 0; i < 7; ++i) {
        size_t need = (size_t)cands[i] * BB * NG * 4
                    + (size_t)cands[i] * BB * 2 * 4
                    + fixed;
        if (need <= ws_size) { Tc = cands[i]; break; }
    }

    char* wsp = (char*)d_ws;
    float* gpre = (float*)wsp; wsp += (size_t)Tc * BB * NG * 4;
    float* shiw = (float*)wsp; wsp += (size_t)Tc * BB * 2 * 4;
    float* shst = (float*)wsp; wsp += (size_t)BB * HH * 4;
    float* scst = (float*)wsp; wsp += (size_t)BB * HH * 4;
    int*   spst = (int*)wsp;   wsp += BB * 4;
    unsigned long long* hbox = (unsigned long long*)wsp;

    kinit<<<dim3(64), 512, 0, stream>>>(hbox);

    const int nch = TT / Tc;
    for (int c = 0; c < nch; ++c) {
        const int t0 = c * Tc;
        kgemm2<<<dim3(8, Tc * 64 / 128), 256, 0, stream>>>(sents, Wih, bih, bhh, gpre, t0);
        kshi<<<dim3(Tc * 16), 256, 0, stream>>>(sents, Waff, baff, shiw, t0);
        krec3<<<dim3(256), 512, 0, stream>>>(gpre, shiw, Whh, mask, out,
                                             shst, scst, spst, hbox,
                                             Wih, tag, Waff, t0, Tc, (c == 0) ? 1 : 0);
    }
}